// Round 2
// baseline (31818.738 us; speedup 1.0000x reference)
//
#include <hip/hip_runtime.h>

// DRNN: 4-layer dilated LSTM, T=2048, dil {1,2,4,8}, dims 256->128->128->128->256.
//
// Round-2 architecture: latency-optimized persistent pipeline, 43 blocks.
//  - zx0_kernel precomputes u0[j] = Wih0@x[j]+bih0+bhh0 (batch GEMM).
//  - R0 (1 block): layer-0 recurrence (dil 1), publishes y0[j].
//  - I1 (1 block): u1[j] = Wih1@y0[j]+b  (streamer, 64-slot ring).
//  - R1 (2 blocks, chain per dil phase): z = u1[j] + Whh1@h -> y1[j].
//  - I2 (1), R2 (4), I3 (2 row-halves), R3 (8 chains x 4 cell-quarters -> d_out).
// All cross-block data/flags are RELAXED agent-scope atomics (sc1: bypass
// L1/L2, ack at LLC). Ordering is manual: s_waitcnt vmcnt(N) + raw s_barrier
// (no compiler release/acquire fences => no L2 writeback/invalidate storms).
// Flags offset by FB so 0 and 0xAAAAAAAA poison both read "not ready"; all
// spins carry budgets so failures are wrong-answer, never hang.

#define TSTEPS 2048
#define FB 1048576

// ws layout in floats
#define ZX_OFF 0
#define Y0_OFF 1048576
#define Y1_OFF 1310720
#define Y2_OFF 1572864
#define U1_OFF 1835008
#define U2_OFF 1867776
#define U3_OFF 1900544
#define FLG_OFF 1966080

#define CBAR() asm volatile("" ::: "memory")
__device__ __forceinline__ void waitvm0() { asm volatile("s_waitcnt vmcnt(0)" ::: "memory"); }
__device__ __forceinline__ void waitvm1() { asm volatile("s_waitcnt vmcnt(1)" ::: "memory"); }
__device__ __forceinline__ void bar_l() {
  asm volatile("s_waitcnt lgkmcnt(0)" ::: "memory");
  __builtin_amdgcn_s_barrier();
  asm volatile("" ::: "memory");
}

__device__ __forceinline__ float f_sig(float x) { return 1.0f / (1.0f + __expf(-x)); }
__device__ __forceinline__ float f_tanh(float x) {
  float xc = fminf(fmaxf(x, -15.0f), 15.0f);
  float e = __expf(2.0f * xc);
  return (e - 1.0f) / (e + 1.0f);
}
__device__ __forceinline__ float g_load(const float* p) {
  return __hip_atomic_load((float*)p, __ATOMIC_RELAXED, __HIP_MEMORY_SCOPE_AGENT);
}
__device__ __forceinline__ void g_store(float* p, float v) {
  __hip_atomic_store(p, v, __ATOMIC_RELAXED, __HIP_MEMORY_SCOPE_AGENT);
}
__device__ __forceinline__ int fl_ld(int* p) {
  return __hip_atomic_load(p, __ATOMIC_RELAXED, __HIP_MEMORY_SCOPE_AGENT);
}
__device__ __forceinline__ void fl_st(int* p, int v) {
  __hip_atomic_store(p, v, __ATOMIC_RELAXED, __HIP_MEMORY_SCOPE_AGENT);
}

// ---------------- kernel 1: zx[j][r] = Wih0[r,:]@x[j,:] + bih0[r] + bhh0[r] ----
__global__ __launch_bounds__(256) void zx0_kernel(
    const float* __restrict__ x, const float* __restrict__ Wih0,
    const float* __restrict__ bih0, const float* __restrict__ bhh0,
    float* __restrict__ zx) {
  __shared__ float xs[4 * 256];
  const int t = threadIdx.x;
  const int j0 = blockIdx.x * 4;
  ((float4*)xs)[t] = ((const float4*)(x + j0 * 256))[t];
  __syncthreads();
  const int r0 = t, r1 = t + 256;
  float a0[4] = {0, 0, 0, 0}, a1[4] = {0, 0, 0, 0};
  const float* w0p = Wih0 + r0 * 256;
  const float* w1p = Wih0 + r1 * 256;
#pragma unroll 8
  for (int k = 0; k < 256; k += 4) {
    float4 wa = *(const float4*)(w0p + k);
    float4 wb = *(const float4*)(w1p + k);
#pragma unroll
    for (int jj = 0; jj < 4; jj++) {
      float4 xv = *(const float4*)(xs + jj * 256 + k);
      a0[jj] += wa.x * xv.x + wa.y * xv.y + wa.z * xv.z + wa.w * xv.w;
      a1[jj] += wb.x * xv.x + wb.y * xv.y + wb.z * xv.z + wb.w * xv.w;
    }
  }
  float b0 = bih0[r0] + bhh0[r0];
  float b1 = bih0[r1] + bhh0[r1];
#pragma unroll
  for (int jj = 0; jj < 4; jj++) {
    zx[(j0 + jj) * 512 + r0] = a0[jj] + b0;
    zx[(j0 + jj) * 512 + r1] = a1[jj] + b1;
  }
}

// ---------------- R0: layer 0, dilation 1, one block, 512 thr ------------------
__device__ void r0_run(int t, const float* __restrict__ Whh0,
                       const float* __restrict__ h00, const float* __restrict__ c00,
                       const float* __restrict__ zx, float* __restrict__ y0,
                       int* __restrict__ F, float* LDS) {
  float* hA = LDS; float* hB = LDS + 128; float* zl = LDS + 256;  // zl[512]
  float w[128];
#pragma unroll
  for (int k = 0; k < 128; k += 4) {
    float4 a = *(const float4*)(Whh0 + t * 128 + k);
    w[k] = a.x; w[k + 1] = a.y; w[k + 2] = a.z; w[k + 3] = a.w;
  }
  float c = 0.0f, hprev = 0.0f;
  if (t < 128) { hA[t] = h00[t]; c = c00[t]; }
  __syncthreads();
  float zxa = zx[t];
  for (int j = 0; j < TSTEPS; j++) {
    if (j > 0 && t < 128) g_store(y0 + (j - 1) * 128 + t, hprev);  // deferred pub
    CBAR();
    float za = zxa;
    if (j + 1 < TSTEPS) zxa = zx[(j + 1) * 512 + t];
    const float* h = (j & 1) ? hB : hA;
    float a0 = 0, a1 = 0, a2 = 0, a3 = 0;
#pragma unroll
    for (int k = 0; k < 128; k += 4) {
      float4 hv = *(const float4*)(h + k);
      a0 += w[k] * hv.x; a1 += w[k + 1] * hv.y;
      a2 += w[k + 2] * hv.z; a3 += w[k + 3] * hv.w;
    }
    zl[t] = za + ((a0 + a1) + (a2 + a3));
    if (t < 128) waitvm1();  // y0 store retired; zx prefetch may stay in flight
    bar_l();
    if (t == 0 && j > 0) fl_st(F + 0, FB + j - 1);
    if (t < 128) {
      float ig = f_sig(zl[t]), fg = f_sig(zl[t + 128]);
      float gg = f_tanh(zl[t + 256]), og = f_sig(zl[t + 384]);
      c = fg * c + ig * gg;
      float h2 = og * f_tanh(c);
      hprev = h2;
      ((j & 1) ? hA : hB)[t] = h2;
    }
    bar_l();
  }
  if (t < 128) g_store(y0 + (TSTEPS - 1) * 128 + t, hprev);
  waitvm0();
  __syncthreads();
  if (t == 0) fl_st(F + 0, FB + TSTEPS - 1);
}

// ---------------- streamer: u[j] = Wih@v[j] + bih + bhh, 64-slot ring ----------
// MODE 0: I1 (in flag 0; guard flags 2..3), 1: I2 (in 2+(j&1); guard 5..8),
// 2: I3 half (in 5+(j&3); guard 11..42)
template <int MODE>
__device__ void streamer_run(int t, int rowoff, const float* __restrict__ Wih,
                             const float* __restrict__ bih, const float* __restrict__ bhh,
                             const float* __restrict__ yin, float* __restrict__ uout,
                             int uw, int myflag, int* __restrict__ F, float* LDS) {
  float* vA = LDS; float* vB = LDS + 128;
  const int r = rowoff + t;
  float w[128];
#pragma unroll
  for (int k = 0; k < 128; k += 4) {
    float4 a = *(const float4*)(Wih + r * 128 + k);
    w[k] = a.x; w[k + 1] = a.y; w[k + 2] = a.z; w[k + 3] = a.w;
  }
  const float bsum = bih[r] + bhh[r];
  int bud = 1 << 21;
  int cf0 = (int)0x80000000, cf1 = cf0, cf2 = cf0, cf3 = cf0;
  if (t < 128) {
    const int fi = (MODE == 0) ? 0 : (MODE == 1) ? 2 : 5;
    int v = fl_ld(F + fi * 16);
    while (v < FB + 0) { if (--bud < 0) break; v = fl_ld(F + fi * 16); }
    CBAR();
    vA[t] = g_load(yin + t);
  }
  __syncthreads();
  float uprev = 0.0f;
  for (int j = 0; j < TSTEPS; j++) {
    // ring-overwrite guard, every 16 steps (covers stores u[j-1 .. j+14])
    if (((j - 1) & 15) == 0 && j >= 65) {
      const int NG = (MODE == 0) ? 2 : (MODE == 1) ? 4 : 32;
      const int G0 = (MODE == 0) ? 2 : (MODE == 1) ? 5 : 11;
      if (t < NG) {
        const int need = FB + j - 50;
        int v = fl_ld(F + (G0 + t) * 16);
        while (v < need) { if (--bud < 0) break; v = fl_ld(F + (G0 + t) * 16); }
      }
      __syncthreads();
    }
    if (j > 0) g_store(uout + ((j - 1) & 63) * uw + r, uprev);
    CBAR();
    const float* v = (j & 1) ? vB : vA;
    float a0 = 0, a1 = 0, a2 = 0, a3 = 0;
#pragma unroll
    for (int k = 0; k < 64; k += 4) {
      float4 vv = *(const float4*)(v + k);
      a0 += w[k] * vv.x; a1 += w[k + 1] * vv.y;
      a2 += w[k + 2] * vv.z; a3 += w[k + 3] * vv.w;
    }
    float regv = 0.0f;
    if (t < 128 && j + 1 < TSTEPS) {
      const int jn = j + 1;
      int fi, cv;
      if (MODE == 0)      { fi = 0;            cv = cf0; }
      else if (MODE == 1) { fi = 2 + (jn & 1); cv = (jn & 1) ? cf1 : cf0; }
      else                { fi = 5 + (jn & 3);
                            cv = ((jn & 3) == 0) ? cf0 : ((jn & 3) == 1) ? cf1
                               : ((jn & 3) == 2) ? cf2 : cf3; }
      if (cv < FB + jn) {
        cv = fl_ld(F + fi * 16);
        while (cv < FB + jn) { if (--bud < 0) break; cv = fl_ld(F + fi * 16); }
        CBAR();
        if (MODE == 0)      cf0 = cv;
        else if (MODE == 1) { if (jn & 1) cf1 = cv; else cf0 = cv; }
        else { if ((jn & 3) == 0) cf0 = cv; else if ((jn & 3) == 1) cf1 = cv;
               else if ((jn & 3) == 2) cf2 = cv; else cf3 = cv; }
      }
      regv = g_load(yin + jn * 128 + t);
    }
#pragma unroll
    for (int k = 64; k < 128; k += 4) {
      float4 vv = *(const float4*)(v + k);
      a0 += w[k] * vv.x; a1 += w[k + 1] * vv.y;
      a2 += w[k + 2] * vv.z; a3 += w[k + 3] * vv.w;
    }
    uprev = bsum + ((a0 + a1) + (a2 + a3));
    if (t < 128) waitvm1(); else waitvm0();  // u store retired; regv may fly
    bar_l();
    if (t == 0 && j > 0) fl_st(F + myflag * 16, FB + j - 1);
    if (t < 128 && j + 1 < TSTEPS) ((j & 1) ? vA : vB)[t] = regv;
    bar_l();
  }
  g_store(uout + ((TSTEPS - 1) & 63) * uw + r, uprev);
  waitvm0();
  __syncthreads();
  if (t == 0) fl_st(F + myflag * 16, FB + TSTEPS - 1);
}

// ---------------- recurrent mid layers: z = u[j] + Whh@h -----------------------
template <int D>
__device__ void recur_run(int q, int t, const float* __restrict__ Whh,
                          const float* __restrict__ h0s, const float* __restrict__ c0s,
                          const float* __restrict__ uin, float* __restrict__ yout,
                          int inflag, int myflag, int* __restrict__ F, float* LDS) {
  float* hA = LDS; float* hB = LDS + 128; float* zl = LDS + 256;  // zl[512]
  float w[128];
#pragma unroll
  for (int k = 0; k < 128; k += 4) {
    float4 a = *(const float4*)(Whh + t * 128 + k);
    w[k] = a.x; w[k + 1] = a.y; w[k + 2] = a.z; w[k + 3] = a.w;
  }
  float c = 0.0f, hprev = 0.0f;
  if (t < 128) { hA[t] = h0s[q * 128 + t]; c = c0s[q * 128 + t]; }
  int bud = 1 << 21;
  int cf = fl_ld(F + inflag * 16);
  while (cf < FB + q) { if (--bud < 0) break; cf = fl_ld(F + inflag * 16); }
  CBAR();
  float regu = g_load(uin + (q & 63) * 512 + t);
  __syncthreads();
  const int NS = TSTEPS / D;
  for (int s = 0; s < NS; s++) {
    const int j = q + s * D;
    if (s > 0 && t < 128) g_store(yout + (j - D) * 128 + t, hprev);
    CBAR();
    const float* h = (s & 1) ? hB : hA;
    float a0 = 0, a1 = 0, a2 = 0, a3 = 0;
#pragma unroll
    for (int k = 0; k < 64; k += 4) {
      float4 hv = *(const float4*)(h + k);
      a0 += w[k] * hv.x; a1 += w[k + 1] * hv.y;
      a2 += w[k + 2] * hv.z; a3 += w[k + 3] * hv.w;
    }
    float regu2 = 0.0f;
    if (s + 1 < NS) {
      const int jn = j + D;
      if (cf < FB + jn) {
        cf = fl_ld(F + inflag * 16);
        while (cf < FB + jn) { if (--bud < 0) break; cf = fl_ld(F + inflag * 16); }
        CBAR();
      }
      regu2 = g_load(uin + (jn & 63) * 512 + t);
    }
#pragma unroll
    for (int k = 64; k < 128; k += 4) {
      float4 hv = *(const float4*)(h + k);
      a0 += w[k] * hv.x; a1 += w[k + 1] * hv.y;
      a2 += w[k + 2] * hv.z; a3 += w[k + 3] * hv.w;
    }
    zl[t] = regu + ((a0 + a1) + (a2 + a3));
    if (t < 128) waitvm1();  // y store retired; regu2 prefetch may fly
    bar_l();
    if (t == 0 && s > 0) fl_st(F + myflag * 16, FB + j - D);
    if (t < 128) {
      float ig = f_sig(zl[t]), fg = f_sig(zl[t + 128]);
      float gg = f_tanh(zl[t + 256]), og = f_sig(zl[t + 384]);
      c = fg * c + ig * gg;
      float h2 = og * f_tanh(c);
      hprev = h2;
      ((s & 1) ? hA : hB)[t] = h2;
    }
    regu = regu2;
    bar_l();
  }
  if (t < 128) g_store(yout + (q + (NS - 1) * D) * 128 + t, hprev);
  waitvm0();
  __syncthreads();
  if (t == 0) fl_st(F + myflag * 16, FB + q + (NS - 1) * D);
}

// ---------------- R3: dil 8, chain q, cell-quarter p, writes d_out -------------
__device__ void r3_run(int q, int p, int t, const float* __restrict__ Whh3,
                       const float* __restrict__ h03, const float* __restrict__ c03,
                       const float* __restrict__ uin, float* __restrict__ out,
                       int* __restrict__ F, float* LDS) {
  float* hA = LDS; float* hB = LDS + 256; float* zp = LDS + 512;  // zp[512]
  const int half = t >> 8;      // k-half
  const int lr = t & 255;       // local row: gate*64 + ci
  const int gate = lr >> 6, ci = lr & 63;
  const int R = gate * 256 + p * 64 + ci;  // global row in [0,1024)
  float w[128];
#pragma unroll
  for (int k = 0; k < 128; k += 4) {
    float4 a = *(const float4*)(Whh3 + R * 256 + half * 128 + k);
    w[k] = a.x; w[k + 1] = a.y; w[k + 2] = a.z; w[k + 3] = a.w;
  }
  float c = 0.0f;
  if (t < 64) c = c03[q * 256 + p * 64 + t];
  if (t < 256) hA[t] = h03[q * 256 + t];
  int bud = 1 << 21;
  const int myflag = 11 + q * 4 + p;
  const int inflag = 9 + ((t >> 7) & 1);  // rows<512 -> flag 9, else 10
  int cf = (int)0x80000000;
  float regu = 0.0f;
  if (t < 256) {
    cf = fl_ld(F + inflag * 16);
    while (cf < FB + q) { if (--bud < 0) break; cf = fl_ld(F + inflag * 16); }
    CBAR();
    regu = g_load(uin + (q & 63) * 1024 + R);
  }
  const int pu = (t < 192) ? (t + (t >= p * 64 ? 64 : 0)) : 0;  // peer cell id
  const int pflag = 11 + q * 4 + (pu >> 6);
  int pcf = (int)0x80000000;
  __syncthreads();
  const int NS = TSTEPS / 8;
  for (int s = 0; s < NS; s++) {
    const int j = q + s * 8;
    const float* h = (s & 1) ? hB : hA;
    float* hn = (s & 1) ? hA : hB;
    float a0 = 0, a1 = 0, a2 = 0, a3 = 0;
#pragma unroll
    for (int k = 0; k < 64; k += 4) {
      float4 hv = *(const float4*)(h + half * 128 + k);
      a0 += w[k] * hv.x; a1 += w[k + 1] * hv.y;
      a2 += w[k + 2] * hv.z; a3 += w[k + 3] * hv.w;
    }
    float regu2 = 0.0f;
    if (s + 1 < NS && t < 256) {
      const int jn = j + 8;
      if (cf < FB + jn) {
        cf = fl_ld(F + inflag * 16);
        while (cf < FB + jn) { if (--bud < 0) break; cf = fl_ld(F + inflag * 16); }
        CBAR();
      }
      regu2 = g_load(uin + (jn & 63) * 1024 + R);
    }
#pragma unroll
    for (int k = 64; k < 128; k += 4) {
      float4 hv = *(const float4*)(h + half * 128 + k);
      a0 += w[k] * hv.x; a1 += w[k + 1] * hv.y;
      a2 += w[k + 2] * hv.z; a3 += w[k + 3] * hv.w;
    }
    zp[t] = ((a0 + a1) + (a2 + a3)) + ((t < 256) ? regu : 0.0f);
    bar_l();
    if (t < 64) {
      float ig = f_sig(zp[t] + zp[256 + t]);
      float fg = f_sig(zp[64 + t] + zp[320 + t]);
      float gg = f_tanh(zp[128 + t] + zp[384 + t]);
      float og = f_sig(zp[192 + t] + zp[448 + t]);
      c = fg * c + ig * gg;
      float h2 = og * f_tanh(c);
      g_store(out + j * 256 + p * 64 + t, h2);
      hn[p * 64 + t] = h2;
      waitvm0();  // own h stores at LLC before flag (same wave as t==0)
    }
    if (t == 0) fl_st(F + myflag * 16, FB + j);
    CBAR();
    if (s + 1 < NS && t < 192) {
      const int need = FB + j;
      if (pcf < need) {
        pcf = fl_ld(F + pflag * 16);
        while (pcf < need) { if (--bud < 0) break; pcf = fl_ld(F + pflag * 16); }
        CBAR();
      }
      hn[pu] = g_load(out + j * 256 + pu);
    }
    if (t < 256) regu = regu2;
    bar_l();
  }
}

// ---------------- persistent pipeline kernel -----------------------------------
__global__ __launch_bounds__(512, 1) void drnn_kernel(
    const float* __restrict__ Whh0, const float* __restrict__ h00, const float* __restrict__ c00,
    const float* __restrict__ Wih1, const float* __restrict__ Whh1,
    const float* __restrict__ bih1, const float* __restrict__ bhh1,
    const float* __restrict__ h01, const float* __restrict__ c01,
    const float* __restrict__ Wih2, const float* __restrict__ Whh2,
    const float* __restrict__ bih2, const float* __restrict__ bhh2,
    const float* __restrict__ h02, const float* __restrict__ c02,
    const float* __restrict__ Wih3, const float* __restrict__ Whh3,
    const float* __restrict__ bih3, const float* __restrict__ bhh3,
    const float* __restrict__ h03, const float* __restrict__ c03,
    float* __restrict__ ws, float* __restrict__ out) {
  __shared__ float LDS[1024];
  const int b = blockIdx.x;
  const int t = threadIdx.x;
  const float* zx = ws + ZX_OFF;
  float* y0 = ws + Y0_OFF;
  float* y1 = ws + Y1_OFF;
  float* y2 = ws + Y2_OFF;
  float* u1 = ws + U1_OFF;
  float* u2 = ws + U2_OFF;
  float* u3 = ws + U3_OFF;
  int* F = (int*)(ws + FLG_OFF);

  if (b == 0) {
    r0_run(t, Whh0, h00, c00, zx, y0, F, LDS);
  } else if (b == 1) {
    streamer_run<0>(t, 0, Wih1, bih1, bhh1, y0, u1, 512, 1, F, LDS);
  } else if (b <= 3) {
    recur_run<2>(b - 2, t, Whh1, h01, c01, u1, y1, 1, 2 + (b - 2), F, LDS);
  } else if (b == 4) {
    streamer_run<1>(t, 0, Wih2, bih2, bhh2, y1, u2, 512, 4, F, LDS);
  } else if (b <= 8) {
    recur_run<4>(b - 5, t, Whh2, h02, c02, u2, y2, 4, 5 + (b - 5), F, LDS);
  } else if (b <= 10) {
    streamer_run<2>(t, (b - 9) * 512, Wih3, bih3, bhh3, y2, u3, 1024, 9 + (b - 9), F, LDS);
  } else {
    const int i = b - 11;
    r3_run(i >> 2, i & 3, t, Whh3, h03, c03, u3, out, F, LDS);
  }
}

extern "C" void kernel_launch(void* const* d_in, const int* in_sizes, int n_in,
                              void* d_out, int out_size, void* d_ws, size_t ws_size,
                              hipStream_t stream) {
  const float* x    = (const float*)d_in[0];
  const float* Wih0 = (const float*)d_in[1];
  const float* Whh0 = (const float*)d_in[2];
  const float* bih0 = (const float*)d_in[3];
  const float* bhh0 = (const float*)d_in[4];
  const float* h00  = (const float*)d_in[5];
  const float* c00  = (const float*)d_in[6];
  const float* Wih1 = (const float*)d_in[7];
  const float* Whh1 = (const float*)d_in[8];
  const float* bih1 = (const float*)d_in[9];
  const float* bhh1 = (const float*)d_in[10];
  const float* h01  = (const float*)d_in[11];
  const float* c01  = (const float*)d_in[12];
  const float* Wih2 = (const float*)d_in[13];
  const float* Whh2 = (const float*)d_in[14];
  const float* bih2 = (const float*)d_in[15];
  const float* bhh2 = (const float*)d_in[16];
  const float* h02  = (const float*)d_in[17];
  const float* c02  = (const float*)d_in[18];
  const float* Wih3 = (const float*)d_in[19];
  const float* Whh3 = (const float*)d_in[20];
  const float* bih3 = (const float*)d_in[21];
  const float* bhh3 = (const float*)d_in[22];
  const float* h03  = (const float*)d_in[23];
  const float* c03  = (const float*)d_in[24];

  float* ws = (float*)d_ws;
  float* zx = ws + ZX_OFF;
  float* out = (float*)d_out;

  zx0_kernel<<<512, 256, 0, stream>>>(x, Wih0, bih0, bhh0, zx);
  drnn_kernel<<<43, 512, 0, stream>>>(Whh0, h00, c00,
                                      Wih1, Whh1, bih1, bhh1, h01, c01,
                                      Wih2, Whh2, bih2, bhh2, h02, c02,
                                      Wih3, Whh3, bih3, bhh3, h03, c03,
                                      ws, out);
}

// Round 3
// 20025.121 us; speedup vs baseline: 1.5889x; 1.5889x over previous
//
#include <hip/hip_runtime.h>

// DRNN: 4-layer dilated LSTM, T=2048, dil {1,2,4,8}, dims 256->128->128->128->256.
//
// Round-3: identical pipeline to round 2 (43 persistent blocks:
//   R0 | I1 | R1 x2 | I2 | R2 x4 | I3 x2 | R3 x32), but all cross-block
// communication switched from agent-scope to SYSTEM-scope relaxed atomics
// (coherence point = MALL; always fresh, no buffer_inv/wbl2 storms), spin
// loops get s_sleep backoff (cuts poll flooding), and flags are padded to
// 256 B. Ordering remains manual: s_waitcnt vmcnt(N) before flag stores.
// Flags offset by FB so 0 and 0xAAAAAAAA both read "not ready"; all spins
// carry budgets so failures are wrong-answer, never hang.

#define TSTEPS 2048
#define FB 1048576

// ws layout in floats
#define ZX_OFF 0
#define Y0_OFF 1048576
#define Y1_OFF 1310720
#define Y2_OFF 1572864
#define U1_OFF 1835008
#define U2_OFF 1867776
#define U3_OFF 1900544
#define FLG_OFF 1966080

#define CBAR() asm volatile("" ::: "memory")
__device__ __forceinline__ void waitvm0() { asm volatile("s_waitcnt vmcnt(0)" ::: "memory"); }
__device__ __forceinline__ void waitvm1() { asm volatile("s_waitcnt vmcnt(1)" ::: "memory"); }
__device__ __forceinline__ void backoff() { asm volatile("s_sleep 1" ::: "memory"); }
__device__ __forceinline__ void bar_l() {
  asm volatile("s_waitcnt lgkmcnt(0)" ::: "memory");
  __builtin_amdgcn_s_barrier();
  asm volatile("" ::: "memory");
}

__device__ __forceinline__ float f_sig(float x) { return 1.0f / (1.0f + __expf(-x)); }
__device__ __forceinline__ float f_tanh(float x) {
  float xc = fminf(fmaxf(x, -15.0f), 15.0f);
  float e = __expf(2.0f * xc);
  return (e - 1.0f) / (e + 1.0f);
}
__device__ __forceinline__ float g_load(const float* p) {
  return __hip_atomic_load((float*)p, __ATOMIC_RELAXED, __HIP_MEMORY_SCOPE_SYSTEM);
}
__device__ __forceinline__ void g_store(float* p, float v) {
  __hip_atomic_store(p, v, __ATOMIC_RELAXED, __HIP_MEMORY_SCOPE_SYSTEM);
}
__device__ __forceinline__ int fl_ld(int* p) {
  return __hip_atomic_load(p, __ATOMIC_RELAXED, __HIP_MEMORY_SCOPE_SYSTEM);
}
__device__ __forceinline__ void fl_st(int* p, int v) {
  __hip_atomic_store(p, v, __ATOMIC_RELAXED, __HIP_MEMORY_SCOPE_SYSTEM);
}

// ---------------- kernel 1: zx[j][r] = Wih0[r,:]@x[j,:] + bih0[r] + bhh0[r] ----
__global__ __launch_bounds__(256) void zx0_kernel(
    const float* __restrict__ x, const float* __restrict__ Wih0,
    const float* __restrict__ bih0, const float* __restrict__ bhh0,
    float* __restrict__ zx) {
  __shared__ float xs[4 * 256];
  const int t = threadIdx.x;
  const int j0 = blockIdx.x * 4;
  ((float4*)xs)[t] = ((const float4*)(x + j0 * 256))[t];
  __syncthreads();
  const int r0 = t, r1 = t + 256;
  float a0[4] = {0, 0, 0, 0}, a1[4] = {0, 0, 0, 0};
  const float* w0p = Wih0 + r0 * 256;
  const float* w1p = Wih0 + r1 * 256;
#pragma unroll 8
  for (int k = 0; k < 256; k += 4) {
    float4 wa = *(const float4*)(w0p + k);
    float4 wb = *(const float4*)(w1p + k);
#pragma unroll
    for (int jj = 0; jj < 4; jj++) {
      float4 xv = *(const float4*)(xs + jj * 256 + k);
      a0[jj] += wa.x * xv.x + wa.y * xv.y + wa.z * xv.z + wa.w * xv.w;
      a1[jj] += wb.x * xv.x + wb.y * xv.y + wb.z * xv.z + wb.w * xv.w;
    }
  }
  float b0 = bih0[r0] + bhh0[r0];
  float b1 = bih0[r1] + bhh0[r1];
#pragma unroll
  for (int jj = 0; jj < 4; jj++) {
    zx[(j0 + jj) * 512 + r0] = a0[jj] + b0;
    zx[(j0 + jj) * 512 + r1] = a1[jj] + b1;
  }
}

// ---------------- R0: layer 0, dilation 1, one block, 512 thr ------------------
__device__ void r0_run(int t, const float* __restrict__ Whh0,
                       const float* __restrict__ h00, const float* __restrict__ c00,
                       const float* __restrict__ zx, float* __restrict__ y0,
                       int* __restrict__ F, float* LDS) {
  float* hA = LDS; float* hB = LDS + 128; float* zl = LDS + 256;  // zl[512]
  float w[128];
#pragma unroll
  for (int k = 0; k < 128; k += 4) {
    float4 a = *(const float4*)(Whh0 + t * 128 + k);
    w[k] = a.x; w[k + 1] = a.y; w[k + 2] = a.z; w[k + 3] = a.w;
  }
  float c = 0.0f, hprev = 0.0f;
  if (t < 128) { hA[t] = h00[t]; c = c00[t]; }
  __syncthreads();
  float zxa = zx[t];
  for (int j = 0; j < TSTEPS; j++) {
    if (j > 0 && t < 128) g_store(y0 + (j - 1) * 128 + t, hprev);  // deferred pub
    CBAR();
    float za = zxa;
    if (j + 1 < TSTEPS) zxa = zx[(j + 1) * 512 + t];
    const float* h = (j & 1) ? hB : hA;
    float a0 = 0, a1 = 0, a2 = 0, a3 = 0;
#pragma unroll
    for (int k = 0; k < 128; k += 4) {
      float4 hv = *(const float4*)(h + k);
      a0 += w[k] * hv.x; a1 += w[k + 1] * hv.y;
      a2 += w[k + 2] * hv.z; a3 += w[k + 3] * hv.w;
    }
    zl[t] = za + ((a0 + a1) + (a2 + a3));
    if (t < 128) waitvm1();  // y0 store retired; zx prefetch may stay in flight
    bar_l();
    if (t == 0 && j > 0) fl_st(F + 0, FB + j - 1);
    if (t < 128) {
      float ig = f_sig(zl[t]), fg = f_sig(zl[t + 128]);
      float gg = f_tanh(zl[t + 256]), og = f_sig(zl[t + 384]);
      c = fg * c + ig * gg;
      float h2 = og * f_tanh(c);
      hprev = h2;
      ((j & 1) ? hA : hB)[t] = h2;
    }
    bar_l();
  }
  if (t < 128) g_store(y0 + (TSTEPS - 1) * 128 + t, hprev);
  waitvm0();
  __syncthreads();
  if (t == 0) fl_st(F + 0, FB + TSTEPS - 1);
}

// ---------------- streamer: u[j] = Wih@v[j] + bih + bhh, 64-slot ring ----------
// MODE 0: I1 (in flag 0; guard flags 2..3), 1: I2 (in 2+(j&1); guard 5..8),
// 2: I3 half (in 5+(j&3); guard 11..42)
template <int MODE>
__device__ void streamer_run(int t, int rowoff, const float* __restrict__ Wih,
                             const float* __restrict__ bih, const float* __restrict__ bhh,
                             const float* __restrict__ yin, float* __restrict__ uout,
                             int uw, int myflag, int* __restrict__ F, float* LDS) {
  float* vA = LDS; float* vB = LDS + 128;
  const int r = rowoff + t;
  float w[128];
#pragma unroll
  for (int k = 0; k < 128; k += 4) {
    float4 a = *(const float4*)(Wih + r * 128 + k);
    w[k] = a.x; w[k + 1] = a.y; w[k + 2] = a.z; w[k + 3] = a.w;
  }
  const float bsum = bih[r] + bhh[r];
  int bud = 1 << 20;
  int cf0 = (int)0x80000000, cf1 = cf0, cf2 = cf0, cf3 = cf0;
  if (t < 128) {
    const int fi = (MODE == 0) ? 0 : (MODE == 1) ? 2 : 5;
    int v = fl_ld(F + fi * 64);
    while (v < FB + 0) { if (--bud < 0) break; backoff(); v = fl_ld(F + fi * 64); }
    CBAR();
    vA[t] = g_load(yin + t);
  }
  __syncthreads();
  float uprev = 0.0f;
  for (int j = 0; j < TSTEPS; j++) {
    // ring-overwrite guard, every 16 steps (covers stores u[j-1 .. j+14])
    if (((j - 1) & 15) == 0 && j >= 65) {
      const int NG = (MODE == 0) ? 2 : (MODE == 1) ? 4 : 32;
      const int G0 = (MODE == 0) ? 2 : (MODE == 1) ? 5 : 11;
      if (t < NG) {
        const int need = FB + j - 50;
        int v = fl_ld(F + (G0 + t) * 64);
        while (v < need) { if (--bud < 0) break; backoff(); v = fl_ld(F + (G0 + t) * 64); }
      }
      __syncthreads();
    }
    if (j > 0) g_store(uout + ((j - 1) & 63) * uw + r, uprev);
    CBAR();
    const float* v = (j & 1) ? vB : vA;
    float a0 = 0, a1 = 0, a2 = 0, a3 = 0;
#pragma unroll
    for (int k = 0; k < 64; k += 4) {
      float4 vv = *(const float4*)(v + k);
      a0 += w[k] * vv.x; a1 += w[k + 1] * vv.y;
      a2 += w[k + 2] * vv.z; a3 += w[k + 3] * vv.w;
    }
    float regv = 0.0f;
    if (t < 128 && j + 1 < TSTEPS) {
      const int jn = j + 1;
      int fi, cv;
      if (MODE == 0)      { fi = 0;            cv = cf0; }
      else if (MODE == 1) { fi = 2 + (jn & 1); cv = (jn & 1) ? cf1 : cf0; }
      else                { fi = 5 + (jn & 3);
                            cv = ((jn & 3) == 0) ? cf0 : ((jn & 3) == 1) ? cf1
                               : ((jn & 3) == 2) ? cf2 : cf3; }
      if (cv < FB + jn) {
        cv = fl_ld(F + fi * 64);
        while (cv < FB + jn) { if (--bud < 0) break; backoff(); cv = fl_ld(F + fi * 64); }
        CBAR();
        if (MODE == 0)      cf0 = cv;
        else if (MODE == 1) { if (jn & 1) cf1 = cv; else cf0 = cv; }
        else { if ((jn & 3) == 0) cf0 = cv; else if ((jn & 3) == 1) cf1 = cv;
               else if ((jn & 3) == 2) cf2 = cv; else cf3 = cv; }
      }
      regv = g_load(yin + jn * 128 + t);
    }
#pragma unroll
    for (int k = 64; k < 128; k += 4) {
      float4 vv = *(const float4*)(v + k);
      a0 += w[k] * vv.x; a1 += w[k + 1] * vv.y;
      a2 += w[k + 2] * vv.z; a3 += w[k + 3] * vv.w;
    }
    uprev = bsum + ((a0 + a1) + (a2 + a3));
    if (t < 128) waitvm1(); else waitvm0();  // u store retired; regv may fly
    bar_l();
    if (t == 0 && j > 0) fl_st(F + myflag * 64, FB + j - 1);
    if (t < 128 && j + 1 < TSTEPS) ((j & 1) ? vA : vB)[t] = regv;
    bar_l();
  }
  g_store(uout + ((TSTEPS - 1) & 63) * uw + r, uprev);
  waitvm0();
  __syncthreads();
  if (t == 0) fl_st(F + myflag * 64, FB + TSTEPS - 1);
}

// ---------------- recurrent mid layers: z = u[j] + Whh@h -----------------------
template <int D>
__device__ void recur_run(int q, int t, const float* __restrict__ Whh,
                          const float* __restrict__ h0s, const float* __restrict__ c0s,
                          const float* __restrict__ uin, float* __restrict__ yout,
                          int inflag, int myflag, int* __restrict__ F, float* LDS) {
  float* hA = LDS; float* hB = LDS + 128; float* zl = LDS + 256;  // zl[512]
  float w[128];
#pragma unroll
  for (int k = 0; k < 128; k += 4) {
    float4 a = *(const float4*)(Whh + t * 128 + k);
    w[k] = a.x; w[k + 1] = a.y; w[k + 2] = a.z; w[k + 3] = a.w;
  }
  float c = 0.0f, hprev = 0.0f;
  if (t < 128) { hA[t] = h0s[q * 128 + t]; c = c0s[q * 128 + t]; }
  int bud = 1 << 20;
  int cf = fl_ld(F + inflag * 64);
  while (cf < FB + q) { if (--bud < 0) break; backoff(); cf = fl_ld(F + inflag * 64); }
  CBAR();
  float regu = g_load(uin + (q & 63) * 512 + t);
  __syncthreads();
  const int NS = TSTEPS / D;
  for (int s = 0; s < NS; s++) {
    const int j = q + s * D;
    if (s > 0 && t < 128) g_store(yout + (j - D) * 128 + t, hprev);
    CBAR();
    const float* h = (s & 1) ? hB : hA;
    float a0 = 0, a1 = 0, a2 = 0, a3 = 0;
#pragma unroll
    for (int k = 0; k < 64; k += 4) {
      float4 hv = *(const float4*)(h + k);
      a0 += w[k] * hv.x; a1 += w[k + 1] * hv.y;
      a2 += w[k + 2] * hv.z; a3 += w[k + 3] * hv.w;
    }
    float regu2 = 0.0f;
    if (s + 1 < NS) {
      const int jn = j + D;
      if (cf < FB + jn) {
        cf = fl_ld(F + inflag * 64);
        while (cf < FB + jn) { if (--bud < 0) break; backoff(); cf = fl_ld(F + inflag * 64); }
        CBAR();
      }
      regu2 = g_load(uin + (jn & 63) * 512 + t);
    }
#pragma unroll
    for (int k = 64; k < 128; k += 4) {
      float4 hv = *(const float4*)(h + k);
      a0 += w[k] * hv.x; a1 += w[k + 1] * hv.y;
      a2 += w[k + 2] * hv.z; a3 += w[k + 3] * hv.w;
    }
    zl[t] = regu + ((a0 + a1) + (a2 + a3));
    if (t < 128) waitvm1();  // y store retired; regu2 prefetch may fly
    bar_l();
    if (t == 0 && s > 0) fl_st(F + myflag * 64, FB + j - D);
    if (t < 128) {
      float ig = f_sig(zl[t]), fg = f_sig(zl[t + 128]);
      float gg = f_tanh(zl[t + 256]), og = f_sig(zl[t + 384]);
      c = fg * c + ig * gg;
      float h2 = og * f_tanh(c);
      hprev = h2;
      ((s & 1) ? hA : hB)[t] = h2;
    }
    regu = regu2;
    bar_l();
  }
  if (t < 128) g_store(yout + (q + (NS - 1) * D) * 128 + t, hprev);
  waitvm0();
  __syncthreads();
  if (t == 0) fl_st(F + myflag * 64, FB + q + (NS - 1) * D);
}

// ---------------- R3: dil 8, chain q, cell-quarter p, writes d_out -------------
__device__ void r3_run(int q, int p, int t, const float* __restrict__ Whh3,
                       const float* __restrict__ h03, const float* __restrict__ c03,
                       const float* __restrict__ uin, float* __restrict__ out,
                       int* __restrict__ F, float* LDS) {
  float* hA = LDS; float* hB = LDS + 256; float* zp = LDS + 512;  // zp[512]
  const int half = t >> 8;      // k-half
  const int lr = t & 255;       // local row: gate*64 + ci
  const int gate = lr >> 6, ci = lr & 63;
  const int R = gate * 256 + p * 64 + ci;  // global row in [0,1024)
  float w[128];
#pragma unroll
  for (int k = 0; k < 128; k += 4) {
    float4 a = *(const float4*)(Whh3 + R * 256 + half * 128 + k);
    w[k] = a.x; w[k + 1] = a.y; w[k + 2] = a.z; w[k + 3] = a.w;
  }
  float c = 0.0f;
  if (t < 64) c = c03[q * 256 + p * 64 + t];
  if (t < 256) hA[t] = h03[q * 256 + t];
  int bud = 1 << 20;
  const int myflag = 11 + q * 4 + p;
  const int inflag = 9 + ((t >> 7) & 1);  // rows<512 -> flag 9, else 10
  int cf = (int)0x80000000;
  float regu = 0.0f;
  if (t < 256) {
    cf = fl_ld(F + inflag * 64);
    while (cf < FB + q) { if (--bud < 0) break; backoff(); cf = fl_ld(F + inflag * 64); }
    CBAR();
    regu = g_load(uin + (q & 63) * 1024 + R);
  }
  const int pu = (t < 192) ? (t + (t >= p * 64 ? 64 : 0)) : 0;  // peer cell id
  const int pflag = 11 + q * 4 + (pu >> 6);
  int pcf = (int)0x80000000;
  __syncthreads();
  const int NS = TSTEPS / 8;
  for (int s = 0; s < NS; s++) {
    const int j = q + s * 8;
    const float* h = (s & 1) ? hB : hA;
    float* hn = (s & 1) ? hA : hB;
    float a0 = 0, a1 = 0, a2 = 0, a3 = 0;
#pragma unroll
    for (int k = 0; k < 64; k += 4) {
      float4 hv = *(const float4*)(h + half * 128 + k);
      a0 += w[k] * hv.x; a1 += w[k + 1] * hv.y;
      a2 += w[k + 2] * hv.z; a3 += w[k + 3] * hv.w;
    }
    float regu2 = 0.0f;
    if (s + 1 < NS && t < 256) {
      const int jn = j + 8;
      if (cf < FB + jn) {
        cf = fl_ld(F + inflag * 64);
        while (cf < FB + jn) { if (--bud < 0) break; backoff(); cf = fl_ld(F + inflag * 64); }
        CBAR();
      }
      regu2 = g_load(uin + (jn & 63) * 1024 + R);
    }
#pragma unroll
    for (int k = 64; k < 128; k += 4) {
      float4 hv = *(const float4*)(h + half * 128 + k);
      a0 += w[k] * hv.x; a1 += w[k + 1] * hv.y;
      a2 += w[k + 2] * hv.z; a3 += w[k + 3] * hv.w;
    }
    zp[t] = ((a0 + a1) + (a2 + a3)) + ((t < 256) ? regu : 0.0f);
    bar_l();
    if (t < 64) {
      float ig = f_sig(zp[t] + zp[256 + t]);
      float fg = f_sig(zp[64 + t] + zp[320 + t]);
      float gg = f_tanh(zp[128 + t] + zp[384 + t]);
      float og = f_sig(zp[192 + t] + zp[448 + t]);
      c = fg * c + ig * gg;
      float h2 = og * f_tanh(c);
      g_store(out + j * 256 + p * 64 + t, h2);
      hn[p * 64 + t] = h2;
      waitvm0();  // own h stores at LLC before flag (same wave as t==0)
    }
    if (t == 0) fl_st(F + myflag * 64, FB + j);
    CBAR();
    if (s + 1 < NS && t < 192) {
      const int need = FB + j;
      if (pcf < need) {
        pcf = fl_ld(F + pflag * 64);
        while (pcf < need) { if (--bud < 0) break; backoff(); pcf = fl_ld(F + pflag * 64); }
        CBAR();
      }
      hn[pu] = g_load(out + j * 256 + pu);
    }
    if (t < 256) regu = regu2;
    bar_l();
  }
}

// ---------------- persistent pipeline kernel -----------------------------------
__global__ __launch_bounds__(512, 1) void drnn_kernel(
    const float* __restrict__ Whh0, const float* __restrict__ h00, const float* __restrict__ c00,
    const float* __restrict__ Wih1, const float* __restrict__ Whh1,
    const float* __restrict__ bih1, const float* __restrict__ bhh1,
    const float* __restrict__ h01, const float* __restrict__ c01,
    const float* __restrict__ Wih2, const float* __restrict__ Whh2,
    const float* __restrict__ bih2, const float* __restrict__ bhh2,
    const float* __restrict__ h02, const float* __restrict__ c02,
    const float* __restrict__ Wih3, const float* __restrict__ Whh3,
    const float* __restrict__ bih3, const float* __restrict__ bhh3,
    const float* __restrict__ h03, const float* __restrict__ c03,
    float* __restrict__ ws, float* __restrict__ out) {
  __shared__ float LDS[1024];
  const int b = blockIdx.x;
  const int t = threadIdx.x;
  const float* zx = ws + ZX_OFF;
  float* y0 = ws + Y0_OFF;
  float* y1 = ws + Y1_OFF;
  float* y2 = ws + Y2_OFF;
  float* u1 = ws + U1_OFF;
  float* u2 = ws + U2_OFF;
  float* u3 = ws + U3_OFF;
  int* F = (int*)(ws + FLG_OFF);

  if (b == 0) {
    r0_run(t, Whh0, h00, c00, zx, y0, F, LDS);
  } else if (b == 1) {
    streamer_run<0>(t, 0, Wih1, bih1, bhh1, y0, u1, 512, 1, F, LDS);
  } else if (b <= 3) {
    recur_run<2>(b - 2, t, Whh1, h01, c01, u1, y1, 1, 2 + (b - 2), F, LDS);
  } else if (b == 4) {
    streamer_run<1>(t, 0, Wih2, bih2, bhh2, y1, u2, 512, 4, F, LDS);
  } else if (b <= 8) {
    recur_run<4>(b - 5, t, Whh2, h02, c02, u2, y2, 4, 5 + (b - 5), F, LDS);
  } else if (b <= 10) {
    streamer_run<2>(t, (b - 9) * 512, Wih3, bih3, bhh3, y2, u3, 1024, 9 + (b - 9), F, LDS);
  } else {
    const int i = b - 11;
    r3_run(i >> 2, i & 3, t, Whh3, h03, c03, u3, out, F, LDS);
  }
}

extern "C" void kernel_launch(void* const* d_in, const int* in_sizes, int n_in,
                              void* d_out, int out_size, void* d_ws, size_t ws_size,
                              hipStream_t stream) {
  const float* x    = (const float*)d_in[0];
  const float* Wih0 = (const float*)d_in[1];
  const float* Whh0 = (const float*)d_in[2];
  const float* bih0 = (const float*)d_in[3];
  const float* bhh0 = (const float*)d_in[4];
  const float* h00  = (const float*)d_in[5];
  const float* c00  = (const float*)d_in[6];
  const float* Wih1 = (const float*)d_in[7];
  const float* Whh1 = (const float*)d_in[8];
  const float* bih1 = (const float*)d_in[9];
  const float* bhh1 = (const float*)d_in[10];
  const float* h01  = (const float*)d_in[11];
  const float* c01  = (const float*)d_in[12];
  const float* Wih2 = (const float*)d_in[13];
  const float* Whh2 = (const float*)d_in[14];
  const float* bih2 = (const float*)d_in[15];
  const float* bhh2 = (const float*)d_in[16];
  const float* h02  = (const float*)d_in[17];
  const float* c02  = (const float*)d_in[18];
  const float* Wih3 = (const float*)d_in[19];
  const float* Whh3 = (const float*)d_in[20];
  const float* bih3 = (const float*)d_in[21];
  const float* bhh3 = (const float*)d_in[22];
  const float* h03  = (const float*)d_in[23];
  const float* c03  = (const float*)d_in[24];

  float* ws = (float*)d_ws;
  float* zx = ws + ZX_OFF;
  float* out = (float*)d_out;

  zx0_kernel<<<512, 256, 0, stream>>>(x, Wih0, bih0, bhh0, zx);
  drnn_kernel<<<43, 512, 0, stream>>>(Whh0, h00, c00,
                                      Wih1, Whh1, bih1, bhh1, h01, c01,
                                      Wih2, Whh2, bih2, bhh2, h02, c02,
                                      Wih3, Whh3, bih3, bhh3, h03, c03,
                                      ws, out);
}

// Round 4
// 4488.060 us; speedup vs baseline: 7.0896x; 4.4619x over previous
//
#include <hip/hip_runtime.h>

// DRNN: 4-layer dilated LSTM, T=2048, dil {1,2,4,8}, dims 256->128->128->128->256.
//
// Round-4: window-batched persistent pipeline, 43 blocks x 512 threads.
//   R0 | I1 | R1 x2 | I2 | R2 x4 | I3 x2 | R3 x32
// All cross-block sync is batched per 8-step window: producers stream data
// stores (no ack wait) and publish ONE flag per window after waitvm0;
// consumers poll once per window (steady state: first poll succeeds).
// u-rings are 256 slots with loose guards (+/-31 windows) so loop closure
// never throttles the pipeline head. System-scope relaxed atomics (MALL
// coherence point) for all cross-block data/flags; no s_sleep (keep waves
// active for DPM residency). Flags offset by FB so 0 / 0xAAAAAAAA both read
// "not ready"; every spin has a budget: failure = wrong answer, never hang.

#define TSTEPS 2048
#define FB 1048576
#define NW 256
#define WSZ 8

// ws layout in floats
#define ZX_OFF 0
#define Y0_OFF 1048576
#define Y1_OFF 1310720
#define Y2_OFF 1572864
#define U1_OFF 1835008
#define U2_OFF 1966080
#define U3_OFF 2097152
#define FLG_OFF 2359296

#define CBAR() asm volatile("" ::: "memory")
__device__ __forceinline__ void waitvm0() { asm volatile("s_waitcnt vmcnt(0)" ::: "memory"); }

__device__ __forceinline__ float f_sig(float x) { return 1.0f / (1.0f + __expf(-x)); }
__device__ __forceinline__ float f_tanh(float x) {
  float xc = fminf(fmaxf(x, -15.0f), 15.0f);
  float e = __expf(2.0f * xc);
  return (e - 1.0f) / (e + 1.0f);
}
__device__ __forceinline__ float g_load(const float* p) {
  return __hip_atomic_load((float*)p, __ATOMIC_RELAXED, __HIP_MEMORY_SCOPE_SYSTEM);
}
__device__ __forceinline__ void g_store(float* p, float v) {
  __hip_atomic_store(p, v, __ATOMIC_RELAXED, __HIP_MEMORY_SCOPE_SYSTEM);
}
__device__ __forceinline__ int fl_ld(int* p) {
  return __hip_atomic_load(p, __ATOMIC_RELAXED, __HIP_MEMORY_SCOPE_SYSTEM);
}
__device__ __forceinline__ void fl_st(int* p, int v) {
  __hip_atomic_store(p, v, __ATOMIC_RELAXED, __HIP_MEMORY_SCOPE_SYSTEM);
}
__device__ __forceinline__ void poll_ge(int* p, int need, int& bud) {
  int v = fl_ld(p);
  while (v < need) { if (--bud < 0) break; v = fl_ld(p); }
  CBAR();
}

// ---------------- kernel 1: zx[j][r] = Wih0[r,:]@x[j,:] + bih0[r] + bhh0[r] ----
__global__ __launch_bounds__(256) void zx0_kernel(
    const float* __restrict__ x, const float* __restrict__ Wih0,
    const float* __restrict__ bih0, const float* __restrict__ bhh0,
    float* __restrict__ zx) {
  __shared__ float xs[4 * 256];
  const int t = threadIdx.x;
  const int j0 = blockIdx.x * 4;
  ((float4*)xs)[t] = ((const float4*)(x + j0 * 256))[t];
  __syncthreads();
  const int r0 = t, r1 = t + 256;
  float a0[4] = {0, 0, 0, 0}, a1[4] = {0, 0, 0, 0};
  const float* w0p = Wih0 + r0 * 256;
  const float* w1p = Wih0 + r1 * 256;
#pragma unroll 8
  for (int k = 0; k < 256; k += 4) {
    float4 wa = *(const float4*)(w0p + k);
    float4 wb = *(const float4*)(w1p + k);
#pragma unroll
    for (int jj = 0; jj < 4; jj++) {
      float4 xv = *(const float4*)(xs + jj * 256 + k);
      a0[jj] += wa.x * xv.x + wa.y * xv.y + wa.z * xv.z + wa.w * xv.w;
      a1[jj] += wb.x * xv.x + wb.y * xv.y + wb.z * xv.z + wb.w * xv.w;
    }
  }
  float b0 = bih0[r0] + bhh0[r0];
  float b1 = bih0[r1] + bhh0[r1];
#pragma unroll
  for (int jj = 0; jj < 4; jj++) {
    zx[(j0 + jj) * 512 + r0] = a0[jj] + b0;
    zx[(j0 + jj) * 512 + r1] = a1[jj] + b1;
  }
}

// ---------------- R0: layer 0, dilation 1, one block ---------------------------
__device__ void r0_run(int t, const float* __restrict__ Whh0,
                       const float* __restrict__ h00, const float* __restrict__ c00,
                       const float* __restrict__ zx, float* __restrict__ y0,
                       int* __restrict__ F, float* LDS) {
  float* hA = LDS; float* hB = LDS + 128; float* zl = LDS + 256;  // zl[512]
  float w[128];
#pragma unroll
  for (int k = 0; k < 128; k += 4) {
    float4 a = *(const float4*)(Whh0 + t * 128 + k);
    w[k] = a.x; w[k + 1] = a.y; w[k + 2] = a.z; w[k + 3] = a.w;
  }
  float c = 0.0f;
  if (t < 128) { hA[t] = h00[t]; c = c00[t]; }
  __syncthreads();
  float zxa = zx[t];
  for (int wi = 0; wi < NW; wi++) {
#pragma unroll 1
    for (int jj = 0; jj < WSZ; jj++) {
      const int j = wi * WSZ + jj;
      float za = zxa;
      if (j + 1 < TSTEPS) zxa = zx[(j + 1) * 512 + t];
      const float* h = (j & 1) ? hB : hA;
      float a0 = 0, a1 = 0, a2 = 0, a3 = 0;
#pragma unroll
      for (int k = 0; k < 128; k += 4) {
        float4 hv = *(const float4*)(h + k);
        a0 += w[k] * hv.x; a1 += w[k + 1] * hv.y;
        a2 += w[k + 2] * hv.z; a3 += w[k + 3] * hv.w;
      }
      zl[t] = za + ((a0 + a1) + (a2 + a3));
      __syncthreads();
      if (t < 128) {
        float ig = f_sig(zl[t]), fg = f_sig(zl[t + 128]);
        float gg = f_tanh(zl[t + 256]), og = f_sig(zl[t + 384]);
        c = fg * c + ig * gg;
        float h2 = og * f_tanh(c);
        ((j & 1) ? hA : hB)[t] = h2;
        g_store(y0 + j * 128 + t, h2);  // fire and forget
      }
      __syncthreads();
    }
    waitvm0();
    __syncthreads();
    if (t == 0) fl_st(F + 0, FB + wi * WSZ + 7);
  }
}

// ---------------- streamers: u[j] = Wih@v[j] + bih + bhh, 256-slot ring --------
// MODE 0: I1 (in F0; guard F2..3) | 1: I2 (in F2..3; guard F5..8)
// | 2: I3 half (in F5..8; guard F11..42)
template <int MODE>
__device__ void streamer_run(int t, int rowoff, const float* __restrict__ Wih,
                             const float* __restrict__ bih, const float* __restrict__ bhh,
                             const float* __restrict__ yin, float* __restrict__ uout,
                             int uw, int myflag, int* __restrict__ F, float* LDS) {
  float* ybuf = LDS;  // [1024]
  const int r = rowoff + t;
  float w[128];
#pragma unroll
  for (int k = 0; k < 128; k += 4) {
    float4 a = *(const float4*)(Wih + r * 128 + k);
    w[k] = a.x; w[k + 1] = a.y; w[k + 2] = a.z; w[k + 3] = a.w;
  }
  const float bsum = bih[r] + bhh[r];
  int bud = 1 << 22;
  for (int wi = 0; wi < NW; wi++) {
    // input-ready poll (one flag per poller thread)
    if (MODE == 0) { if (t == 0) poll_ge(F + 0, FB + wi * 8 + 7, bud); }
    else if (MODE == 1) { if (t < 2) poll_ge(F + (2 + t) * 64, FB + wi * 8 + 6 + t, bud); }
    else { if (t < 4) poll_ge(F + (5 + t) * 64, FB + wi * 8 + 4 + t, bud); }
    // ring-overwrite guard (ring=256 slots, tolerance 31 windows)
    if (wi >= 32) {
      const int need = FB + wi * 8 - 250;
      if (MODE == 0) { if (t < 2) poll_ge(F + (2 + t) * 64, need, bud); }
      else if (MODE == 1) { if (t < 4) poll_ge(F + (5 + t) * 64, need, bud); }
      else { if (t < 32) poll_ge(F + (11 + t) * 64, need, bud); }
    }
    __syncthreads();
    // stage window inputs (8 x 128) into LDS
    float va = g_load(yin + wi * 1024 + t);
    float vb = g_load(yin + wi * 1024 + 512 + t);
    ybuf[t] = va; ybuf[512 + t] = vb;
    __syncthreads();
#pragma unroll 1
    for (int jj = 0; jj < WSZ; jj++) {
      const float* v = ybuf + jj * 128;
      float a0 = 0, a1 = 0, a2 = 0, a3 = 0;
#pragma unroll
      for (int k = 0; k < 128; k += 4) {
        float4 vv = *(const float4*)(v + k);
        a0 += w[k] * vv.x; a1 += w[k + 1] * vv.y;
        a2 += w[k + 2] * vv.z; a3 += w[k + 3] * vv.w;
      }
      const int j = wi * 8 + jj;
      g_store(uout + (j & 255) * uw + r, bsum + ((a0 + a1) + (a2 + a3)));
    }
    waitvm0();
    __syncthreads();
    if (t == 0) fl_st(F + myflag * 64, FB + wi * 8 + 7);
  }
}

// ---------------- recurrent mid layers: z = u[j] + Whh@h -----------------------
template <int D>
__device__ void recur_run(int q, int t, const float* __restrict__ Whh,
                          const float* __restrict__ h0s, const float* __restrict__ c0s,
                          const float* __restrict__ uin, float* __restrict__ yout,
                          int inflag, int myflag, int* __restrict__ F, float* LDS) {
  float* hA = LDS; float* hB = LDS + 128; float* zl = LDS + 256;  // zl[512]
  float w[128];
#pragma unroll
  for (int k = 0; k < 128; k += 4) {
    float4 a = *(const float4*)(Whh + t * 128 + k);
    w[k] = a.x; w[k + 1] = a.y; w[k + 2] = a.z; w[k + 3] = a.w;
  }
  float c = 0.0f;
  if (t < 128) { hA[t] = h0s[q * 128 + t]; c = c0s[q * 128 + t]; }
  int bud = 1 << 22;
  __syncthreads();
  const int NC = WSZ / D;
  int s = 0;
  for (int wi = 0; wi < NW; wi++) {
    if (t == 0) poll_ge(F + inflag * 64, FB + wi * 8 + 7, bud);
    __syncthreads();
    float ur[NC];
#pragma unroll
    for (int k = 0; k < NC; k++)
      ur[k] = g_load(uin + ((wi * 8 + q + k * D) & 255) * 512 + t);
#pragma unroll 1
    for (int k = 0; k < NC; k++) {
      const int j = wi * 8 + q + k * D;
      const float* h = (s & 1) ? hB : hA;
      float a0 = 0, a1 = 0, a2 = 0, a3 = 0;
#pragma unroll
      for (int kk = 0; kk < 128; kk += 4) {
        float4 hv = *(const float4*)(h + kk);
        a0 += w[kk] * hv.x; a1 += w[kk + 1] * hv.y;
        a2 += w[kk + 2] * hv.z; a3 += w[kk + 3] * hv.w;
      }
      zl[t] = ur[k] + ((a0 + a1) + (a2 + a3));
      __syncthreads();
      if (t < 128) {
        float ig = f_sig(zl[t]), fg = f_sig(zl[t + 128]);
        float gg = f_tanh(zl[t + 256]), og = f_sig(zl[t + 384]);
        c = fg * c + ig * gg;
        float h2 = og * f_tanh(c);
        ((s & 1) ? hA : hB)[t] = h2;
        g_store(yout + j * 128 + t, h2);
      }
      s++;
      __syncthreads();
    }
    waitvm0();
    __syncthreads();
    if (t == 0) fl_st(F + myflag * 64, FB + wi * 8 + q + (NC - 1) * D);
  }
}

// ---------------- R3: dil 8, chain q, cell-quarter p, writes d_out -------------
__device__ void r3_run(int q, int p, int t, const float* __restrict__ Whh3,
                       const float* __restrict__ h03, const float* __restrict__ c03,
                       const float* __restrict__ uin, float* __restrict__ out,
                       int* __restrict__ F, float* LDS) {
  float* hA = LDS; float* hB = LDS + 256; float* zp = LDS + 512;  // zp[512]
  const int half = t >> 8;
  const int lr = t & 255;
  const int gate = lr >> 6, ci = lr & 63;
  const int R = gate * 256 + p * 64 + ci;  // global row in [0,1024)
  float w[128];
#pragma unroll
  for (int k = 0; k < 128; k += 4) {
    float4 a = *(const float4*)(Whh3 + R * 256 + half * 128 + k);
    w[k] = a.x; w[k + 1] = a.y; w[k + 2] = a.z; w[k + 3] = a.w;
  }
  float c = 0.0f;
  if (t < 64) c = c03[q * 256 + p * 64 + t];
  if (t < 256) hA[t] = h03[q * 256 + t];
  int bud = 1 << 22;
  const int myflag = 11 + q * 4 + p;
  const int pu = (t < 192) ? (t + (t >= p * 64 ? 64 : 0)) : 0;  // peer cell id
  const int pflag = 11 + q * 4 + (pu >> 6);
  __syncthreads();
  for (int wi = 0; wi < NW; wi++) {
    const int j = wi * 8 + q;
    if (t == 0) poll_ge(F + 9 * 64, FB + wi * 8 + 7, bud);
    if (t == 1) poll_ge(F + 10 * 64, FB + wi * 8 + 7, bud);
    __syncthreads();
    float u = 0.0f;
    if (t < 256) u = g_load(uin + (j & 255) * 1024 + R);
    const float* h = (wi & 1) ? hB : hA;
    float* hn = (wi & 1) ? hA : hB;
    float a0 = 0, a1 = 0, a2 = 0, a3 = 0;
#pragma unroll
    for (int k = 0; k < 128; k += 4) {
      float4 hv = *(const float4*)(h + half * 128 + k);
      a0 += w[k] * hv.x; a1 += w[k + 1] * hv.y;
      a2 += w[k + 2] * hv.z; a3 += w[k + 3] * hv.w;
    }
    zp[t] = ((a0 + a1) + (a2 + a3)) + ((t < 256) ? u : 0.0f);
    __syncthreads();
    if (t < 64) {
      float ig = f_sig(zp[t] + zp[256 + t]);
      float fg = f_sig(zp[64 + t] + zp[320 + t]);
      float gg = f_tanh(zp[128 + t] + zp[384 + t]);
      float og = f_sig(zp[192 + t] + zp[448 + t]);
      c = fg * c + ig * gg;
      float h2 = og * f_tanh(c);
      g_store(out + j * 256 + p * 64 + t, h2);
      hn[p * 64 + t] = h2;
      waitvm0();  // own h stores at LLC before flag (t==0 is in this wave)
    }
    __syncthreads();
    if (t == 0) fl_st(F + myflag * 64, FB + j);
    if (t < 192) {
      poll_ge(F + pflag * 64, FB + j, bud);
      hn[pu] = g_load(out + j * 256 + pu);
    }
    __syncthreads();
  }
}

// ---------------- persistent pipeline kernel -----------------------------------
__global__ __launch_bounds__(512, 1) void drnn_kernel(
    const float* __restrict__ Whh0, const float* __restrict__ h00, const float* __restrict__ c00,
    const float* __restrict__ Wih1, const float* __restrict__ Whh1,
    const float* __restrict__ bih1, const float* __restrict__ bhh1,
    const float* __restrict__ h01, const float* __restrict__ c01,
    const float* __restrict__ Wih2, const float* __restrict__ Whh2,
    const float* __restrict__ bih2, const float* __restrict__ bhh2,
    const float* __restrict__ h02, const float* __restrict__ c02,
    const float* __restrict__ Wih3, const float* __restrict__ Whh3,
    const float* __restrict__ bih3, const float* __restrict__ bhh3,
    const float* __restrict__ h03, const float* __restrict__ c03,
    float* __restrict__ ws, float* __restrict__ out) {
  __shared__ float LDS[1024];
  const int b = blockIdx.x;
  const int t = threadIdx.x;
  const float* zx = ws + ZX_OFF;
  float* y0 = ws + Y0_OFF;
  float* y1 = ws + Y1_OFF;
  float* y2 = ws + Y2_OFF;
  float* u1 = ws + U1_OFF;
  float* u2 = ws + U2_OFF;
  float* u3 = ws + U3_OFF;
  int* F = (int*)(ws + FLG_OFF);

  if (b == 0) {
    r0_run(t, Whh0, h00, c00, zx, y0, F, LDS);
  } else if (b == 1) {
    streamer_run<0>(t, 0, Wih1, bih1, bhh1, y0, u1, 512, 1, F, LDS);
  } else if (b <= 3) {
    recur_run<2>(b - 2, t, Whh1, h01, c01, u1, y1, 1, 2 + (b - 2), F, LDS);
  } else if (b == 4) {
    streamer_run<1>(t, 0, Wih2, bih2, bhh2, y1, u2, 512, 4, F, LDS);
  } else if (b <= 8) {
    recur_run<4>(b - 5, t, Whh2, h02, c02, u2, y2, 4, 5 + (b - 5), F, LDS);
  } else if (b <= 10) {
    streamer_run<2>(t, (b - 9) * 512, Wih3, bih3, bhh3, y2, u3, 1024, 9 + (b - 9), F, LDS);
  } else {
    const int i = b - 11;
    r3_run(i >> 2, i & 3, t, Whh3, h03, c03, u3, out, F, LDS);
  }
}

extern "C" void kernel_launch(void* const* d_in, const int* in_sizes, int n_in,
                              void* d_out, int out_size, void* d_ws, size_t ws_size,
                              hipStream_t stream) {
  const float* x    = (const float*)d_in[0];
  const float* Wih0 = (const float*)d_in[1];
  const float* Whh0 = (const float*)d_in[2];
  const float* bih0 = (const float*)d_in[3];
  const float* bhh0 = (const float*)d_in[4];
  const float* h00  = (const float*)d_in[5];
  const float* c00  = (const float*)d_in[6];
  const float* Wih1 = (const float*)d_in[7];
  const float* Whh1 = (const float*)d_in[8];
  const float* bih1 = (const float*)d_in[9];
  const float* bhh1 = (const float*)d_in[10];
  const float* h01  = (const float*)d_in[11];
  const float* c01  = (const float*)d_in[12];
  const float* Wih2 = (const float*)d_in[13];
  const float* Whh2 = (const float*)d_in[14];
  const float* bih2 = (const float*)d_in[15];
  const float* bhh2 = (const float*)d_in[16];
  const float* h02  = (const float*)d_in[17];
  const float* c02  = (const float*)d_in[18];
  const float* Wih3 = (const float*)d_in[19];
  const float* Whh3 = (const float*)d_in[20];
  const float* bih3 = (const float*)d_in[21];
  const float* bhh3 = (const float*)d_in[22];
  const float* h03  = (const float*)d_in[23];
  const float* c03  = (const float*)d_in[24];

  float* ws = (float*)d_ws;
  float* zx = ws + ZX_OFF;
  float* out = (float*)d_out;

  zx0_kernel<<<512, 256, 0, stream>>>(x, Wih0, bih0, bhh0, zx);
  drnn_kernel<<<43, 512, 0, stream>>>(Whh0, h00, c00,
                                      Wih1, Whh1, bih1, bhh1, h01, c01,
                                      Wih2, Whh2, bih2, bhh2, h02, c02,
                                      Wih3, Whh3, bih3, bhh3, h03, c03,
                                      ws, out);
}

// Round 5
// 2114.933 us; speedup vs baseline: 15.0448x; 2.1221x over previous
//
#include <hip/hip_runtime.h>

// DRNN: 4-layer dilated LSTM, T=2048, dil {1,2,4,8}, dims 256->128->128->128->256.
//
// Round-5: tag-riding dataflow pipeline, 41 persistent blocks x 512 threads.
//   R0 | I1 | R1 x2 | I2 | R2 x4 | R3 (8 chains x 4 cell-quarters, Wih3 inlined)
// Every cross-block float is an 8-byte (tag<<32|bits) pair stored by ONE relaxed
// system-scope atomic. NO flags, NO waitvm0, NO release fences. Consumers
// speculatively prefetch the next window during compute and validate tags at
// use (retry w/ budget). Barriers are raw s_barrier + lgkmcnt(0) ONLY -- stores
// are never drained inside loops (__syncthreads would vmcnt(0)-drain to MALL
// every step; that was round-4's hidden 17us/window serializer).
// Ring guards: producers check consumer OUTPUT tags (progress) at 28-window
// slack on 32-window rings. Poison 0xAA.. gives negative tags => "not ready".
// Every poll has a budget: failure = wrong answer, never hang.

typedef unsigned long long ull;

#define TSTEPS 2048
#define FB 1048576
#define NW 256

// ws layout: float zx[2048*512] then ull region
#define ZX_FLOATS 1048576
#define U1_OFF 0        // 256*512 ull
#define U2_OFF 131072   // 256*512
#define Y0_OFF 262144   // 256*128
#define Y1_OFF 294912   // 256*128
#define Y2_OFF 327680   // 256*128
#define HX_OFF 360448   // 256*256

__device__ __forceinline__ void barL() {
  asm volatile("s_waitcnt lgkmcnt(0)\ns_barrier" ::: "memory");
}
__device__ __forceinline__ float f_sig(float x) { return 1.0f / (1.0f + __expf(-x)); }
__device__ __forceinline__ float f_tanh(float x) {
  float xc = fminf(fmaxf(x, -15.0f), 15.0f);
  float e = __expf(2.0f * xc);
  return (e - 1.0f) / (e + 1.0f);
}
__device__ __forceinline__ ull pld(const ull* p) {
  return __hip_atomic_load((ull*)p, __ATOMIC_RELAXED, __HIP_MEMORY_SCOPE_SYSTEM);
}
__device__ __forceinline__ void pst(ull* p, int tag, float v) {
  ull u = (((ull)(unsigned)tag) << 32) | (ull)__float_as_uint(v);
  __hip_atomic_store(p, u, __ATOMIC_RELAXED, __HIP_MEMORY_SCOPE_SYSTEM);
}
__device__ __forceinline__ int ptag(ull u) { return (int)(u >> 32); }
__device__ __forceinline__ float pval(ull u) { return __uint_as_float((unsigned)u); }
__device__ __forceinline__ void ensure(ull& u, const ull* p, int need, int& bud) {
  while (ptag(u) < need) { if (--bud < 0) break; u = pld(p); }
}
__device__ __forceinline__ void pollg(const ull* p, int need, int& bud) {
  ull g = pld(p);
  while (ptag(g) < need) { if (--bud < 0) break; g = pld(p); }
}

// ---------------- kernel 1: zx[j][r] = Wih0[r,:]@x[j,:] + bih0[r] + bhh0[r] ----
__global__ __launch_bounds__(256) void zx0_kernel(
    const float* __restrict__ x, const float* __restrict__ Wih0,
    const float* __restrict__ bih0, const float* __restrict__ bhh0,
    float* __restrict__ zx) {
  __shared__ float xs[4 * 256];
  const int t = threadIdx.x;
  const int j0 = blockIdx.x * 4;
  ((float4*)xs)[t] = ((const float4*)(x + j0 * 256))[t];
  __syncthreads();
  const int r0 = t, r1 = t + 256;
  float a0[4] = {0, 0, 0, 0}, a1[4] = {0, 0, 0, 0};
  const float* w0p = Wih0 + r0 * 256;
  const float* w1p = Wih0 + r1 * 256;
#pragma unroll 8
  for (int k = 0; k < 256; k += 4) {
    float4 wa = *(const float4*)(w0p + k);
    float4 wb = *(const float4*)(w1p + k);
#pragma unroll
    for (int jj = 0; jj < 4; jj++) {
      float4 xv = *(const float4*)(xs + jj * 256 + k);
      a0[jj] += wa.x * xv.x + wa.y * xv.y + wa.z * xv.z + wa.w * xv.w;
      a1[jj] += wb.x * xv.x + wb.y * xv.y + wb.z * xv.z + wb.w * xv.w;
    }
  }
  float b0 = bih0[r0] + bhh0[r0];
  float b1 = bih0[r1] + bhh0[r1];
#pragma unroll
  for (int jj = 0; jj < 4; jj++) {
    zx[(j0 + jj) * 512 + r0] = a0[jj] + b0;
    zx[(j0 + jj) * 512 + r1] = a1[jj] + b1;
  }
}

// ---------------- R0: layer 0, dil 1. split-k: thread=(half,r0) rows r0,r0+256 --
__device__ void r0_run(int t, const float* __restrict__ Whh0,
                       const float* __restrict__ h00, const float* __restrict__ c00,
                       const float* __restrict__ zx, ull* __restrict__ y0,
                       const ull* __restrict__ u1, float* LDS) {
  float* hA = LDS; float* hB = LDS + 128; float* zp = LDS + 256;  // zp[1024]
  const int half = t >> 8, r0 = t & 255;
  float w0[64], w1[64];
#pragma unroll
  for (int k = 0; k < 64; k += 4) {
    float4 a = *(const float4*)(Whh0 + r0 * 128 + half * 64 + k);
    w0[k] = a.x; w0[k + 1] = a.y; w0[k + 2] = a.z; w0[k + 3] = a.w;
    float4 b = *(const float4*)(Whh0 + (r0 + 256) * 128 + half * 64 + k);
    w1[k] = b.x; w1[k + 1] = b.y; w1[k + 2] = b.z; w1[k + 3] = b.w;
  }
  float c = 0.0f;
  if (t < 128) { hA[t] = h00[t]; c = c00[t]; }
  int bud = 1 << 21;
  float zxa = 0, zxb = 0;
  if (half == 0) { zxa = zx[r0]; zxb = zx[256 + r0]; }
  __syncthreads();
  for (int j = 0; j < TSTEPS; j++) {
    if ((j & 7) == 0 && j >= 224) {  // ring guard: I1 consumed j-224
      const int jg = j - 224;
      if (t == 0) pollg(u1 + (ull)(jg & 255) * 512, FB + jg, bud);
    }
    const float* h = ((j & 1) ? hB : hA) + half * 64;
    float a0 = 0, a1 = 0, b0 = 0, b1 = 0;
#pragma unroll
    for (int k = 0; k < 64; k += 4) {
      float4 hv = *(const float4*)(h + k);
      a0 += w0[k] * hv.x + w0[k + 1] * hv.y; a1 += w0[k + 2] * hv.z + w0[k + 3] * hv.w;
      b0 += w1[k] * hv.x + w1[k + 1] * hv.y; b1 += w1[k + 2] * hv.z + w1[k + 3] * hv.w;
    }
    float za = a0 + a1, zb = b0 + b1;
    if (half == 0) { za += zxa; zb += zxb; }
    zp[half * 512 + r0] = za; zp[half * 512 + r0 + 256] = zb;
    if (half == 0 && j + 1 < TSTEPS) {  // prefetch zx(j+1), latency hidden next step
      zxa = zx[(j + 1) * 512 + r0]; zxb = zx[(j + 1) * 512 + 256 + r0];
    }
    barL();
    if (t < 128) {
      float zi = zp[t] + zp[512 + t];
      float zf = zp[128 + t] + zp[640 + t];
      float zg = zp[256 + t] + zp[768 + t];
      float zo = zp[384 + t] + zp[896 + t];
      float ig = f_sig(zi), fg = f_sig(zf), gg = f_tanh(zg), og = f_sig(zo);
      c = fg * c + ig * gg;
      float h2 = og * f_tanh(c);
      ((j & 1) ? hA : hB)[t] = h2;
      pst(y0 + (ull)(j & 255) * 128 + t, FB + j, h2);  // fire & forget
    }
    barL();
  }
}

// ---------------- streamers I1/I2: u[j] = Wih@v[j]+b. GN = #consumer chains ----
template <int GN>
__device__ void istream_run(int t, const float* __restrict__ Wih,
                            const float* __restrict__ bih, const float* __restrict__ bhh,
                            const ull* __restrict__ yin, ull* __restrict__ uout,
                            const ull* __restrict__ gb, float* LDS) {
  float* yb = LDS;            // [1024] window inputs
  float* zpA = LDS + 1024;    // [1024]
  float* zpB = LDS + 2048;    // [1024]
  const int half = t >> 8, r0 = t & 255;
  float w0[64], w1[64];
#pragma unroll
  for (int k = 0; k < 64; k += 4) {
    float4 a = *(const float4*)(Wih + r0 * 128 + half * 64 + k);
    w0[k] = a.x; w0[k + 1] = a.y; w0[k + 2] = a.z; w0[k + 3] = a.w;
    float4 b = *(const float4*)(Wih + (r0 + 256) * 128 + half * 64 + k);
    w1[k] = b.x; w1[k + 1] = b.y; w1[k + 2] = b.z; w1[k + 3] = b.w;
  }
  const float bst = bih[t] + bhh[t];  // bias of row t (store phase)
  int bud = 1 << 21;
  ull pf0 = 0, pf1 = 0;
  __syncthreads();
  for (int wi = 0; wi < NW; wi++) {
    const int jb = wi * 8;
    const int j0 = jb + (t >> 7), j1 = j0 + 4;
    ensure(pf0, yin + (ull)(j0 & 255) * 128 + (t & 127), FB + j0, bud);
    ensure(pf1, yin + (ull)(j1 & 255) * 128 + (t & 127), FB + j1, bud);
    yb[t] = pval(pf0); yb[512 + t] = pval(pf1);
    barL();
    if (wi + 1 < NW) {  // speculative prefetch next window
      const int n0 = jb + 8 + (t >> 7), n1 = n0 + 4;
      pf0 = pld(yin + (ull)(n0 & 255) * 128 + (t & 127));
      pf1 = pld(yin + (ull)(n1 & 255) * 128 + (t & 127));
    }
    if (wi >= 28 && t < GN) {  // ring guard via consumer output tags
      const int jg = jb - 224 + t;
      pollg(gb + (ull)(jg & 255) * 128, FB + jg, bud);
    }
#pragma unroll 1
    for (int jj = 0; jj < 8; jj++) {
      float* zp = (jj & 1) ? zpB : zpA;
      const float* v = yb + jj * 128 + half * 64;
      float a0 = 0, a1 = 0, b0 = 0, b1 = 0;
#pragma unroll
      for (int k = 0; k < 64; k += 4) {
        float4 vv = *(const float4*)(v + k);
        a0 += w0[k] * vv.x + w0[k + 1] * vv.y; a1 += w0[k + 2] * vv.z + w0[k + 3] * vv.w;
        b0 += w1[k] * vv.x + w1[k + 1] * vv.y; b1 += w1[k + 2] * vv.z + w1[k + 3] * vv.w;
      }
      zp[half * 512 + r0] = a0 + a1; zp[half * 512 + r0 + 256] = b0 + b1;
      barL();
      const float uv = zp[t] + zp[512 + t] + bst;
      pst(uout + (ull)((jb + jj) & 255) * 512 + t, FB + jb + jj, uv);
      // no 2nd barrier: zp double-buffered; next jj's barrier protects reuse
    }
    barL();  // yb reuse next window
  }
}

// ---------------- R1/R2: z = u[j] + Whh@h. D=dilation, GMODE guard type -------
template <int D, int GMODE>
__device__ void rmid_run(int q, int t, const float* __restrict__ Whh,
                         const float* __restrict__ h0s, const float* __restrict__ c0s,
                         const ull* __restrict__ uin, ull* __restrict__ yout,
                         const ull* __restrict__ gb, float* LDS) {
  float* hA = LDS; float* hB = LDS + 128; float* zp = LDS + 256;  // zp[1024]
  const int half = t >> 8, r0 = t & 255;
  const int NC = 8 / D;
  float w0[64], w1[64];
#pragma unroll
  for (int k = 0; k < 64; k += 4) {
    float4 a = *(const float4*)(Whh + r0 * 128 + half * 64 + k);
    w0[k] = a.x; w0[k + 1] = a.y; w0[k + 2] = a.z; w0[k + 3] = a.w;
    float4 b = *(const float4*)(Whh + (r0 + 256) * 128 + half * 64 + k);
    w1[k] = b.x; w1[k + 1] = b.y; w1[k + 2] = b.z; w1[k + 3] = b.w;
  }
  float c = 0.0f;
  if (t < 128) { hA[t] = h0s[q * 128 + t]; c = c0s[q * 128 + t]; }
  int bud = 1 << 21;
  ull pf[2 * NC];
#pragma unroll
  for (int k = 0; k < 2 * NC; k++) pf[k] = 0;
  __syncthreads();
  int s = 0;
  for (int wi = 0; wi < NW; wi++) {
    const int jb = wi * 8 + q;
    float uva[NC], uvb[NC];
    if (half == 0) {
#pragma unroll
      for (int k = 0; k < NC; k++) {
        const int jk = jb + k * D;
        ensure(pf[2 * k], uin + (ull)(jk & 255) * 512 + r0, FB + jk, bud);
        ensure(pf[2 * k + 1], uin + (ull)(jk & 255) * 512 + r0 + 256, FB + jk, bud);
        uva[k] = pval(pf[2 * k]); uvb[k] = pval(pf[2 * k + 1]);
      }
      if (wi + 1 < NW) {
#pragma unroll
        for (int k = 0; k < NC; k++) {
          const int jn = jb + 8 + k * D;
          pf[2 * k] = pld(uin + (ull)(jn & 255) * 512 + r0);
          pf[2 * k + 1] = pld(uin + (ull)(jn & 255) * 512 + r0 + 256);
        }
      }
    } else {
#pragma unroll
      for (int k = 0; k < NC; k++) { uva[k] = 0; uvb[k] = 0; }
    }
    if (wi >= 28) {  // ring guard
      if (GMODE == 1) {  // R1: I2 progress via u2 tags (whole-window consumer)
        if (t == 0) { const int jg = wi * 8 - 224; pollg(gb + (ull)(jg & 255) * 512, FB + jg, bud); }
      } else {           // R2: R3 chains q, q+4 progress via hx tags
        if (t < 2) { const int jg = wi * 8 - 224 + q + t * 4; pollg(gb + (ull)(jg & 255) * 256, FB + jg, bud); }
      }
    }
#pragma unroll 1
    for (int k = 0; k < NC; k++) {
      const int j = jb + k * D;
      const float* h = ((s & 1) ? hB : hA) + half * 64;
      float a0 = 0, a1 = 0, b0 = 0, b1 = 0;
#pragma unroll
      for (int kk = 0; kk < 64; kk += 4) {
        float4 hv = *(const float4*)(h + kk);
        a0 += w0[kk] * hv.x + w0[kk + 1] * hv.y; a1 += w0[kk + 2] * hv.z + w0[kk + 3] * hv.w;
        b0 += w1[kk] * hv.x + w1[kk + 1] * hv.y; b1 += w1[kk + 2] * hv.z + w1[kk + 3] * hv.w;
      }
      float za = a0 + a1, zb = b0 + b1;
      if (half == 0) { za += uva[k]; zb += uvb[k]; }
      zp[half * 512 + r0] = za; zp[half * 512 + r0 + 256] = zb;
      barL();
      if (t < 128) {
        float zi = zp[t] + zp[512 + t];
        float zf = zp[128 + t] + zp[640 + t];
        float zg = zp[256 + t] + zp[768 + t];
        float zo = zp[384 + t] + zp[896 + t];
        float ig = f_sig(zi), fg = f_sig(zf), gg = f_tanh(zg), og = f_sig(zo);
        c = fg * c + ig * gg;
        float h2 = og * f_tanh(c);
        ((s & 1) ? hA : hB)[t] = h2;
        pst(yout + (ull)(j & 255) * 128 + t, FB + j, h2);
      }
      s++;
      barL();
    }
  }
}

// ---------------- R3: dil 8, chain q, quarter p, Wih3 inlined, writes d_out ----
__device__ void r3_run(int q, int p, int t, const float* __restrict__ Wih3,
                       const float* __restrict__ Whh3,
                       const float* __restrict__ bih3, const float* __restrict__ bhh3,
                       const float* __restrict__ h03, const float* __restrict__ c03,
                       const ull* __restrict__ y2, ull* __restrict__ hx,
                       float* __restrict__ out, float* LDS) {
  float* hA = LDS;         // 256
  float* hB = LDS + 256;   // 256
  float* zp = LDS + 512;   // 512
  float* yA = LDS + 1024;  // 128
  float* yB = LDS + 1152;  // 128
  const int half = t >> 8, lr = t & 255, ci = lr & 63;
  const int R = (lr >> 6) * 256 + p * 64 + ci;  // global z-row
  float wh[128], wx[64];
#pragma unroll
  for (int k = 0; k < 128; k += 4) {
    float4 a = *(const float4*)(Whh3 + R * 256 + half * 128 + k);
    wh[k] = a.x; wh[k + 1] = a.y; wh[k + 2] = a.z; wh[k + 3] = a.w;
  }
#pragma unroll
  for (int k = 0; k < 64; k += 4) {
    float4 a = *(const float4*)(Wih3 + R * 128 + half * 64 + k);
    wx[k] = a.x; wx[k + 1] = a.y; wx[k + 2] = a.z; wx[k + 3] = a.w;
  }
  const float bst = (half == 0) ? (bih3[R] + bhh3[R]) : 0.0f;
  float c = (t < 64) ? c03[q * 256 + p * 64 + t] : 0.0f;
  if (t < 256) hA[t] = h03[q * 256 + t];
  int bud = 1 << 21;
  ull ypf = 0;
  const int pu = (t >= 64 && t < 256) ? (((t - 64) < p * 64) ? (t - 64) : (t - 64) + 64) : 0;
  __syncthreads();
#pragma unroll 1
  for (int s = 0; s < 256; s++) {
    const int j = q + 8 * s;
    float* ycur = (s & 1) ? yB : yA;
    if (t < 128) {
      ensure(ypf, y2 + (ull)(j & 255) * 128 + t, FB + j, bud);
      ycur[t] = pval(ypf);
    }
    barL();
    if (t < 128 && s + 1 < 256) ypf = pld(y2 + (ull)((j + 8) & 255) * 128 + t);
    const float* h = ((s & 1) ? hB : hA) + half * 128;
    const float* yv = ycur + half * 64;
    float* hn = (s & 1) ? hA : hB;
    float a0 = 0, a1 = 0;
#pragma unroll
    for (int k = 0; k < 64; k += 4) {
      float4 vv = *(const float4*)(yv + k);
      a0 += wx[k] * vv.x + wx[k + 1] * vv.y; a1 += wx[k + 2] * vv.z + wx[k + 3] * vv.w;
    }
#pragma unroll
    for (int k = 0; k < 128; k += 4) {
      float4 hv = *(const float4*)(h + k);
      a0 += wh[k] * hv.x + wh[k + 1] * hv.y; a1 += wh[k + 2] * hv.z + wh[k + 3] * hv.w;
    }
    zp[t] = a0 + a1 + bst;
    barL();
    if (t < 64) {
      float zi = zp[t] + zp[256 + t];
      float zf = zp[64 + t] + zp[320 + t];
      float zg = zp[128 + t] + zp[384 + t];
      float zo = zp[192 + t] + zp[448 + t];
      float ig = f_sig(zi), fg = f_sig(zf), gg = f_tanh(zg), og = f_sig(zo);
      c = fg * c + ig * gg;
      float h2 = og * f_tanh(c);
      out[j * 256 + p * 64 + t] = h2;                      // final output (plain)
      pst(hx + (ull)(j & 255) * 256 + p * 64 + t, FB + j, h2);  // peer broadcast
      hn[p * 64 + t] = h2;
    }
    if (s + 1 < 256 && t >= 64 && t < 256) {  // gather 192 peer cells
      const ull* pp = hx + (ull)(j & 255) * 256 + pu;
      ull hu = pld(pp);
      while (ptag(hu) < FB + j) { if (--bud < 0) break; hu = pld(pp); }
      hn[pu] = pval(hu);
    }
    barL();
  }
}

// ---------------- persistent pipeline kernel -----------------------------------
__global__ __launch_bounds__(512, 2) void drnn_kernel(
    const float* __restrict__ Whh0, const float* __restrict__ h00, const float* __restrict__ c00,
    const float* __restrict__ Wih1, const float* __restrict__ Whh1,
    const float* __restrict__ bih1, const float* __restrict__ bhh1,
    const float* __restrict__ h01, const float* __restrict__ c01,
    const float* __restrict__ Wih2, const float* __restrict__ Whh2,
    const float* __restrict__ bih2, const float* __restrict__ bhh2,
    const float* __restrict__ h02, const float* __restrict__ c02,
    const float* __restrict__ Wih3, const float* __restrict__ Whh3,
    const float* __restrict__ bih3, const float* __restrict__ bhh3,
    const float* __restrict__ h03, const float* __restrict__ c03,
    float* __restrict__ ws, float* __restrict__ out) {
  __shared__ float LDS[3072];
  const int b = blockIdx.x;
  const int t = threadIdx.x;
  const float* zx = ws;
  ull* base8 = (ull*)(ws + ZX_FLOATS);
  ull* u1 = base8 + U1_OFF;
  ull* u2 = base8 + U2_OFF;
  ull* y0 = base8 + Y0_OFF;
  ull* y1 = base8 + Y1_OFF;
  ull* y2 = base8 + Y2_OFF;
  ull* hx = base8 + HX_OFF;

  if (b == 0) {
    r0_run(t, Whh0, h00, c00, zx, y0, u1, LDS);
  } else if (b == 1) {
    istream_run<2>(t, Wih1, bih1, bhh1, y0, u1, y1, LDS);
  } else if (b <= 3) {
    rmid_run<2, 1>(b - 2, t, Whh1, h01, c01, u1, y1, u2, LDS);
  } else if (b == 4) {
    istream_run<4>(t, Wih2, bih2, bhh2, y1, u2, y2, LDS);
  } else if (b <= 8) {
    rmid_run<4, 2>(b - 5, t, Whh2, h02, c02, u2, y2, hx, LDS);
  } else {
    const int i = b - 9;
    r3_run(i >> 2, i & 3, t, Wih3, Whh3, bih3, bhh3, h03, c03, y2, hx, out, LDS);
  }
}

extern "C" void kernel_launch(void* const* d_in, const int* in_sizes, int n_in,
                              void* d_out, int out_size, void* d_ws, size_t ws_size,
                              hipStream_t stream) {
  const float* x    = (const float*)d_in[0];
  const float* Wih0 = (const float*)d_in[1];
  const float* Whh0 = (const float*)d_in[2];
  const float* bih0 = (const float*)d_in[3];
  const float* bhh0 = (const float*)d_in[4];
  const float* h00  = (const float*)d_in[5];
  const float* c00  = (const float*)d_in[6];
  const float* Wih1 = (const float*)d_in[7];
  const float* Whh1 = (const float*)d_in[8];
  const float* bih1 = (const float*)d_in[9];
  const float* bhh1 = (const float*)d_in[10];
  const float* h01  = (const float*)d_in[11];
  const float* c01  = (const float*)d_in[12];
  const float* Wih2 = (const float*)d_in[13];
  const float* Whh2 = (const float*)d_in[14];
  const float* bih2 = (const float*)d_in[15];
  const float* bhh2 = (const float*)d_in[16];
  const float* h02  = (const float*)d_in[17];
  const float* c02  = (const float*)d_in[18];
  const float* Wih3 = (const float*)d_in[19];
  const float* Whh3 = (const float*)d_in[20];
  const float* bih3 = (const float*)d_in[21];
  const float* bhh3 = (const float*)d_in[22];
  const float* h03  = (const float*)d_in[23];
  const float* c03  = (const float*)d_in[24];

  float* ws = (float*)d_ws;
  float* out = (float*)d_out;

  zx0_kernel<<<512, 256, 0, stream>>>(x, Wih0, bih0, bhh0, ws);
  drnn_kernel<<<41, 512, 0, stream>>>(Whh0, h00, c00,
                                      Wih1, Whh1, bih1, bhh1, h01, c01,
                                      Wih2, Whh2, bih2, bhh2, h02, c02,
                                      Wih3, Whh3, bih3, bhh3, h03, c03,
                                      ws, out);
}